// Round 3
// baseline (278.048 us; speedup 1.0000x reference)
//
#include <hip/hip_runtime.h>

// ChannelBlockImportanceGate: B=8, C=256, H=W=132, BLOCK=8, KEEP_RATIO=0.25
// Output = hard top-72 block mask (of 289 blocks) upsampled 8x, per (b,c) plane.
// Straight-through soft blend cancels numerically -> output is the hard mask.
//
// v3: (a) atomic-free phase 1 — thread-per-block register accumulation
//     (16 float4 loads/block, fp64-exact sum, zero LDS contention);
//     (b) rank via sortable-u32 keys (top 32 bits of non-negative f64 are
//     order-monotone) with 1-cy u32 compares; exact f64 fallback on key
//     ties (e>1), which is ~never taken but keeps bit-exact semantics;
//     (c) NT float4 stores (don't evict L3-resident input).

#define HH 132
#define WW 132
#define NB 17          // blocks per side (ceil(132/8) = 17)
#define TOTAL 289      // NB*NB
#define NPAD 320       // padded key/score count (multiple of 64)
#define KEEP 72        // round(289*0.25)
#define NTHREADS 256
#define NV ((HH * WW) / 4)   // 4356 float4s per plane (132%4==0)

typedef float floatx4 __attribute__((ext_vector_type(4)));

__global__ __launch_bounds__(NTHREADS)
void gate_kernel(const float4* __restrict__ feats4,
                 const int* __restrict__ enabled_p,
                 float4* __restrict__ out4) {
    const int plane = blockIdx.x;            // b*C + c, 0..2047
    const int t = threadIdx.x;
    const float4* __restrict__ fp = feats4 + (size_t)plane * NV;
    floatx4* __restrict__ op = (floatx4*)(out4 + (size_t)plane * NV);

    __shared__ __align__(16) double   s_score[NPAD];
    __shared__ __align__(16) unsigned s_key[NPAD];
    __shared__ float s_hard[TOTAL];

    // ---- Phase 1: per-thread block sums, fp64-exact, NO atomics ----
    // Block (br,bc): rows br*8..+nr, float4-cols bc*2..+hc (right edge col
    // 128..131 is a single float4; bottom edge has 4 real rows, pad is 0).
    for (int b = t; b < TOTAL; b += NTHREADS) {
        const int br = b / NB;
        const int bc = b - br * NB;
        const int nr = (br == NB - 1) ? 4 : 8;
        const int hc = (bc == NB - 1) ? 1 : 2;
        const float4* bp = fp + br * (8 * 33) + bc * 2;
        double a0 = 0.0, a1 = 0.0;
        #pragma unroll
        for (int rr = 0; rr < 8; ++rr) {
            if (rr < nr) {
                const float4 x = bp[rr * 33];
                a0 += (double)fabsf(x.x) + (double)fabsf(x.y)
                    + (double)fabsf(x.z) + (double)fabsf(x.w);
                if (hc == 2) {
                    const float4 y = bp[rr * 33 + 1];
                    a1 += (double)fabsf(y.x) + (double)fabsf(y.y)
                        + (double)fabsf(y.z) + (double)fabsf(y.w);
                }
            }
        }
        s_score[b] = a0 + a1;
    }
    if (t < NPAD - TOTAL) s_score[TOTAL + t] = 0.0;   // pad -> key 0
    __syncthreads();

    // ---- Phase 2a: sortable u32 keys (sums >= 0 -> hi32 bits monotone) ----
    for (int i = t; i < NPAD; i += NTHREADS) {
        s_key[i] = (unsigned)((unsigned long long)
                       __double_as_longlong(s_score[i]) >> 32);
    }
    __syncthreads();

    // ---- Phase 2b: top-72 by stable rank, u32 fast path ----
    const int en = *enabled_p;
    const uint4* __restrict__ sk4 = (const uint4*)s_key;
    for (int i = t; i < TOTAL; i += NTHREADS) {
        const unsigned ki = s_key[i];
        int r = 0, e = 0;
        #pragma unroll 10
        for (int q = 0; q < NPAD / 4; ++q) {       // 80 uint4 broadcast reads
            const uint4 k = sk4[q];
            r += (int)(k.x > ki) + (int)(k.y > ki)
               + (int)(k.z > ki) + (int)(k.w > ki);
            e += (int)(k.x == ki) + (int)(k.y == ki)
               + (int)(k.z == ki) + (int)(k.w == ki);
        }
        int rank = r;                               // e==1: exact (self only)
        if (e > 1) {                                // key tie: exact f64 rank
            const double si = s_score[i];
            rank = 0;
            for (int j = 0; j < TOTAL; ++j) {
                const double sj = s_score[j];
                rank += (int)((sj > si) || ((sj == si) && (j < i)));
            }
        }
        s_hard[i] = (!en || rank < KEEP) ? 1.0f : 0.0f;
    }
    __syncthreads();

    // ---- Phase 3: upsample 8x, nontemporal float4 stores ----
    for (int v = t; v < NV; v += NTHREADS) {
        const int base = v * 4;
        const int row = base / WW;                  // magic-mul division
        const int col = base - row * WW;
        const float m = s_hard[(row >> 3) * NB + (col >> 3)];
        const floatx4 mv = {m, m, m, m};
        __builtin_nontemporal_store(mv, &op[v]);
    }
}

extern "C" void kernel_launch(void* const* d_in, const int* in_sizes, int n_in,
                              void* d_out, int out_size, void* d_ws, size_t ws_size,
                              hipStream_t stream) {
    const float4* feats = (const float4*)d_in[0];
    const int* enabled = (const int*)d_in[1];
    float4* out = (float4*)d_out;
    const int planes = 8 * 256;              // B*C = 2048
    gate_kernel<<<planes, NTHREADS, 0, stream>>>(feats, enabled, out);
}